// Round 9
// baseline (486.012 us; speedup 1.0000x reference)
//
#include <hip/hip_runtime.h>
#include <hip/hip_bf16.h>

typedef unsigned short u16;
typedef unsigned char u8;
typedef unsigned int u32;
typedef __attribute__((ext_vector_type(8))) short short8;
typedef __attribute__((ext_vector_type(4))) float f32x4;

#define NN 8192
#define KIN 256
#define FOUT 128
#define KW 2048              // K-window per wave (4 waves x 2048 = full 8192)
#define L2E 1.4426950408889634f

__device__ __forceinline__ float exp2fast(float x) { return __builtin_amdgcn_exp2f(x); }

__device__ __forceinline__ u16 f2bf(float f) {
    u32 u = __float_as_uint(f);
    u32 r = ((u >> 16) & 1u) + 0x7fffu;
    return (u16)((u + r) >> 16);
}
__device__ __forceinline__ u32 pk_bf16(float a, float b) {
    union { __hip_bfloat162 h2; u32 u; } cv;
    cv.h2 = __float22bfloat162_rn(make_float2(a, b));
    return cv.u;
}
__device__ __forceinline__ u32 fkey(float f) {
    u32 b = __float_as_uint(f);
    return (b & 0x80000000u) ? ~b : (b | 0x80000000u);
}
__device__ __forceinline__ float funkey(u32 k) {
    u32 b = (k & 0x80000000u) ? (k & 0x7fffffffu) : ~k;
    return __uint_as_float(b);
}

// ---------------- K1: Wh = h@W (fp32 acc) -> whfrag (B-fragment-major bf16), src, dst*log2e, gmax
// whfrag: [(kstep*8 + ntile)*64 + lane]*8 u16, elem j = Wh[kstep*32+(lane>>4)*8+j][ntile*16+(lane&15)]
__global__ __launch_bounds__(256) void k1_wh(
    const float* __restrict__ h, const float* __restrict__ W, const float* __restrict__ a,
    u16* __restrict__ whfrag,
    float* __restrict__ src, float* __restrict__ dl2e, u32* __restrict__ gmaxk)
{
    __shared__ float hT[64][36];
    __shared__ u16   lt[128][40];
    __shared__ float sd[32][2];
    const int t  = threadIdx.x;
    const int m0 = blockIdx.x * 32;
    const int rq = t >> 5, cq = t & 31;

    float acc[4][4];
#pragma unroll
    for (int i = 0; i < 4; i++)
#pragma unroll
        for (int j = 0; j < 4; j++) acc[i][j] = 0.f;
    if (t < 64) sd[t >> 1][t & 1] = 0.f;

    for (int kt = 0; kt < KIN; kt += 64) {
        __syncthreads();
#pragma unroll
        for (int s2 = 0; s2 < 2; s2++) {
            int f = s2 * 256 + t;
            int r = f >> 4, kc = (f & 15) * 4;
            float4 hv = *(const float4*)(h + (size_t)(m0 + r) * KIN + kt + kc);
            hT[kc + 0][r] = hv.x; hT[kc + 1][r] = hv.y;
            hT[kc + 2][r] = hv.z; hT[kc + 3][r] = hv.w;
        }
        __syncthreads();
        for (int k = 0; k < 64; k++) {
            float4 wv = *(const float4*)(W + (size_t)(kt + k) * FOUT + cq * 4);
            float h0 = hT[k][rq * 4 + 0], h1 = hT[k][rq * 4 + 1];
            float h2 = hT[k][rq * 4 + 2], h3 = hT[k][rq * 4 + 3];
            acc[0][0] += h0 * wv.x; acc[0][1] += h0 * wv.y; acc[0][2] += h0 * wv.z; acc[0][3] += h0 * wv.w;
            acc[1][0] += h1 * wv.x; acc[1][1] += h1 * wv.y; acc[1][2] += h1 * wv.z; acc[1][3] += h1 * wv.w;
            acc[2][0] += h2 * wv.x; acc[2][1] += h2 * wv.y; acc[2][2] += h2 * wv.z; acc[2][3] += h2 * wv.w;
            acc[3][0] += h3 * wv.x; acc[3][1] += h3 * wv.y; acc[3][2] += h3 * wv.z; acc[3][3] += h3 * wv.w;
        }
    }
#pragma unroll
    for (int i = 0; i < 4; i++) {
        float sp = 0.f, dp = 0.f;
#pragma unroll
        for (int j = 0; j < 4; j++) {
            sp += acc[i][j] * a[cq * 4 + j];
            dp += acc[i][j] * a[FOUT + cq * 4 + j];
            lt[cq * 4 + j][rq * 4 + i] = f2bf(acc[i][j]);
        }
        atomicAdd(&sd[rq * 4 + i][0], sp);
        atomicAdd(&sd[rq * 4 + i][1], dp);
    }
    __syncthreads();
    if (t < 32) { src[m0 + t] = sd[t][0]; dl2e[m0 + t] = sd[t][1] * L2E; }
    if (t < 64) {
        float v = (t < 32) ? sd[t][1] : -3.0e38f;
#pragma unroll
        for (int off = 32; off >= 1; off >>= 1) v = fmaxf(v, __shfl_down(v, off));
        if (t == 0) atomicMax(gmaxk, fkey(v));
    }
    const int kstep = blockIdx.x;
#pragma unroll
    for (int p = 0; p < 2; p++) {
        int f = p * 256 + t;
        int nt = f >> 6;
        int l  = f & 63;
        short8 v = *(const short8*)&lt[nt * 16 + (l & 15)][(l >> 4) * 8];
        *(short8*)(whfrag + ((size_t)(kstep * 8 + nt) * 64 + l) * 8) = v;
    }
}

// ---------------- K2: one-pass fused attention. Block = 16 rows x full K=8192. ------
// Phase A: each wave reads its 16x2048 adj window in long sequential 8KB row-runs,
//          packs mask nibbles into wave-private LDS (8 KB).
// Phase B: barrier-free MFMA loop off LDS masks (R8 structure, no global mask loads).
// Epilogue: ONE __syncthreads; cross-wave K-reduction + exact softmax normalize -> out.
__global__ __launch_bounds__(256, 4) void k2_attn(
    const int* __restrict__ adj, const float* __restrict__ src, const float* __restrict__ dl2e,
    const u16* __restrict__ whfrag, const u32* __restrict__ gmaxk,
    float* __restrict__ out)
{
    __shared__ u8  mask[4][16][512];     // 32 KB; reused as fp32 exchange after phase B
    __shared__ u16 Pall[4][16][40];      // 5 KB; P tile, then psum exchange
    const int t = threadIdx.x;
    const int lane = t & 63, wave = t >> 6;
    const int i0 = blockIdx.x * 16;
    const int l15 = lane & 15, quad = lane >> 4;
    const int r0 = lane >> 3, r1 = 8 + r0;
    const int co = (lane & 7) * 4;
    const int cbase = wave * KW;

    // ---- phase A: adj -> mask nibbles (wave-private, no barriers) ----
#pragma unroll
    for (int r = 0; r < 16; r++) {
        const int* ap = adj + (size_t)(i0 + r) * NN + cbase;
#pragma unroll
        for (int c = 0; c < 8; c++) {
            int4 v = *(const int4*)(ap + c * 256 + lane * 4);
            mask[wave][r][c * 64 + lane] =
                (u8)((v.x > 0) | ((v.y > 0) << 1) | ((v.z > 0) << 2) | ((v.w > 0) << 3));
        }
    }

    // per-lane row softmax constants
    const float gm = funkey(*gmaxk) * L2E;
    float s0 = src[i0 + r0] * L2E, s1 = src[i0 + r1] * L2E;
    float xm0 = s0 + gm, xm1 = s1 + gm;
    float C0 = fmaxf(xm0, 0.01f * xm0), C1 = fmaxf(xm1, 0.01f * xm1);
    const float y10 = s0 - C0, y20 = 0.01f * s0 - C0;
    const float y11 = s1 - C1, y21 = 0.01f * s1 - C1;

    u16 (*P)[40] = Pall[wave];
    f32x4 acc[8];
#pragma unroll
    for (int nt = 0; nt < 8; nt++) acc[nt] = {0.f, 0.f, 0.f, 0.f};
    float ps0 = 0.f, ps1 = 0.f;

    // ---- phase B: 64 k-steps of 32 cols ----
    for (int kk = 0; kk < 64; ++kk) {
        const int kb = cbase + kk * 32;

        // B fragments (L2): issue first so latency hides under P compute
        uint4 bv[8];
        const u16* wf = whfrag + ((size_t)((kb >> 5) * 8) * 64 + lane) * 8;
#pragma unroll
        for (int nt = 0; nt < 8; nt++)
            bv[nt] = *(const uint4*)(wf + (size_t)nt * 64 * 8);

        u32 n0 = mask[wave][r0][kk * 8 + (lane & 7)];
        u32 n1 = mask[wave][r1][kk * 8 + (lane & 7)];
        float4 d = *(const float4*)(dl2e + kb + co);
        {
            float x, p0, p1, p2, p3;
            x = fmaxf(y10 + d.x, y20 + 0.01f * d.x); p0 = exp2fast((n0 & 1u) ? x : -1.0e9f);
            x = fmaxf(y10 + d.y, y20 + 0.01f * d.y); p1 = exp2fast((n0 & 2u) ? x : -1.0e9f);
            x = fmaxf(y10 + d.z, y20 + 0.01f * d.z); p2 = exp2fast((n0 & 4u) ? x : -1.0e9f);
            x = fmaxf(y10 + d.w, y20 + 0.01f * d.w); p3 = exp2fast((n0 & 8u) ? x : -1.0e9f);
            ps0 += (p0 + p1) + (p2 + p3);
            *(uint2*)&P[r0][co] = make_uint2(pk_bf16(p0, p1), pk_bf16(p2, p3));
            x = fmaxf(y11 + d.x, y21 + 0.01f * d.x); p0 = exp2fast((n1 & 1u) ? x : -1.0e9f);
            x = fmaxf(y11 + d.y, y21 + 0.01f * d.y); p1 = exp2fast((n1 & 2u) ? x : -1.0e9f);
            x = fmaxf(y11 + d.z, y21 + 0.01f * d.z); p2 = exp2fast((n1 & 4u) ? x : -1.0e9f);
            x = fmaxf(y11 + d.w, y21 + 0.01f * d.w); p3 = exp2fast((n1 & 8u) ? x : -1.0e9f);
            ps1 += (p0 + p1) + (p2 + p3);
            *(uint2*)&P[r1][co] = make_uint2(pk_bf16(p0, p1), pk_bf16(p2, p3));
        }

        // A fragment via wave-private LDS transpose (same-wave DS ops are ordered)
        short8 af = *(const short8*)&P[l15][quad * 8];

#pragma unroll
        for (int nt = 0; nt < 8; nt++) {
            union { uint4 q; short8 s8; } bf; bf.q = bv[nt];
            acc[nt] = __builtin_amdgcn_mfma_f32_16x16x32_bf16(af, bf.s8, acc[nt], 0, 0, 0);
        }
    }

    // ---- epilogue: cross-wave K reduction + normalize ----
    // row-sum partials: 8 lanes per row
    ps0 += __shfl_down(ps0, 4, 8); ps0 += __shfl_down(ps0, 2, 8); ps0 += __shfl_down(ps0, 1, 8);
    ps1 += __shfl_down(ps1, 4, 8); ps1 += __shfl_down(ps1, 2, 8); ps1 += __shfl_down(ps1, 1, 8);
    float* pf = (float*)&Pall[wave][0][0];       // P tile dead; reuse for 16 psums
    if ((lane & 7) == 0) { pf[r0] = ps0; pf[r1] = ps1; }

    // acc tile -> exchange LDS in row-major (C/D: col=lane&15, row=quad*4+reg)
    float* ex = (float*)&mask[wave][0][0];       // masks dead; 16x128 fp32 = 8 KB
    {
        int crow = quad * 4, ccol = l15;
#pragma unroll
        for (int nt = 0; nt < 8; nt++)
#pragma unroll
            for (int reg = 0; reg < 4; reg++)
                ex[(crow + reg) * FOUT + nt * 16 + ccol] = acc[nt][reg];
    }
    __syncthreads();

    {
        int row = t >> 4, c8 = (t & 15) * 8;
        float s[8];
#pragma unroll
        for (int j = 0; j < 8; j++) s[j] = 0.f;
        float l = 0.f;
#pragma unroll
        for (int w = 0; w < 4; w++) {
            const float* exw = (const float*)&mask[w][0][0];
            const float* pfw = (const float*)&Pall[w][0][0];
            float4 v0 = *(const float4*)&exw[row * FOUT + c8];
            float4 v1 = *(const float4*)&exw[row * FOUT + c8 + 4];
            s[0] += v0.x; s[1] += v0.y; s[2] += v0.z; s[3] += v0.w;
            s[4] += v1.x; s[5] += v1.y; s[6] += v1.z; s[7] += v1.w;
            l += pfw[row];
        }
        float ri = 1.0f / l;
        float* op = out + (size_t)(i0 + row) * FOUT + c8;
        *(float4*)op       = make_float4(s[0] * ri, s[1] * ri, s[2] * ri, s[3] * ri);
        *(float4*)(op + 4) = make_float4(s[4] * ri, s[5] * ri, s[6] * ri, s[7] * ri);
    }
}

extern "C" void kernel_launch(void* const* d_in, const int* in_sizes, int n_in,
                              void* d_out, int out_size, void* d_ws, size_t ws_size,
                              hipStream_t stream) {
    const float* h   = (const float*)d_in[0];
    const int*   adj = (const int*)d_in[1];
    const float* W   = (const float*)d_in[2];
    const float* a   = (const float*)d_in[3];
    float* out = (float*)d_out;

    char* ws = (char*)d_ws;
    u16*   whfrag = (u16*)ws;                           // 2 MB
    float* src    = (float*)(ws + (2u << 20));          // 32 KB
    float* dl2e   = src + NN;                           // 32 KB
    u32*   gmaxk  = (u32*)(dl2e + NN);                  // 4 B

    (void)hipMemsetAsync(gmaxk, 0, sizeof(u32), stream);
    k1_wh<<<dim3(NN / 32), dim3(256), 0, stream>>>(h, W, a, whfrag, src, dl2e, gmaxk);
    k2_attn<<<dim3(NN / 16), dim3(256), 0, stream>>>(adj, src, dl2e, whfrag, gmaxk, out);
}